// Round 15
// baseline (184.115 us; speedup 1.0000x reference)
//
#include <hip/hip_runtime.h>

#define NFEAT 64
#define BNODES 64            // nodes per dst-bucket (bucket = dst >> 6)
#define MAXBUCK 1024         // supports N <= 65536 (edge packing needs N <= 65536)
#define SORT_LDS 6144        // whole-bucket LDS staging for in-place sort path
#define KPT 4                // edges per thread in k_part (register-staged)
#define NPW 16               // nodes per wave in epilogue passes

__device__ __forceinline__ int load_idx(const int* __restrict__ ei, long long elem, int is64) {
    return is64 ? ei[2 * elem] : ei[(int)elem];
}

// bf16 round-to-nearest-even-ish (RN with tie bump; fine for finite data)
__device__ __forceinline__ unsigned short f2bf(float f) {
    unsigned int u = __float_as_uint(f);
    return (unsigned short)((u + 0x7FFFu + ((u >> 16) & 1u)) >> 16);
}
__device__ __forceinline__ float bf2f(unsigned short h) {
    return __uint_as_float(((unsigned int)h) << 16);
}

// ------- zero bcnt (replaces hipMemsetAsync; one tiny block) ----------------
__global__ void k_zero(int* __restrict__ p, int n) {
    for (int i = threadIdx.x; i < n; i += 1024) p[i] = 0;
}

// ------- bucket-level histogram (782 counters; LDS hist + merge) ------------
// Self-detects int64 vs int32 edge encoding: values < 65536, so under int64
// every odd int32 word is 0 (probe 256 odd words; all-zero => int64).
__global__ __launch_bounds__(256) void k_histb(
        const int* __restrict__ ei, int* __restrict__ bcnt, int E, int nb) {
    __shared__ int h[MAXBUCK];
    __shared__ int s_not64;
    if (threadIdx.x == 0) s_not64 = 0;
    for (int i = threadIdx.x; i < nb; i += 256) h[i] = 0;
    __syncthreads();
    if (ei[2 * threadIdx.x + 1] != 0) s_not64 = 1;   // benign same-value race
    __syncthreads();
    int is64 = s_not64 ? 0 : 1;
    int per = (E + gridDim.x - 1) / gridDim.x;
    int e0 = blockIdx.x * per;
    int e1 = min(e0 + per, E);
    for (int i = e0 + threadIdx.x; i < e1; i += 256) {
        int d = load_idx(ei, (long long)E + i, is64);
        atomicAdd(&h[d >> 6], 1);
    }
    __syncthreads();
    for (int i = threadIdx.x; i < nb; i += 256)
        if (h[i]) atomicAdd(&bcnt[i], h[i]);
}

// ------- exclusive scan of bucket counts (+ sentinel) ------------------------
__global__ void k_bscan(const int* __restrict__ bcnt, int* __restrict__ bstart,
                        int* __restrict__ bfill, int nb, int E) {
    __shared__ int s[1024];
    int t = threadIdx.x;
    int mine = (t < nb) ? bcnt[t] : 0;
    s[t] = mine;
    __syncthreads();
    for (int off = 1; off < 1024; off <<= 1) {
        int v = (t >= off) ? s[t - off] : 0;
        __syncthreads();
        s[t] += v;
        __syncthreads();
    }
    if (t < nb) {
        int excl = s[t] - mine;
        bstart[t] = excl;
        bfill[t] = excl;
    }
    if (t == 0) bstart[nb] = E;   // sentinel
}

// ------- partition edges into dst-buckets, packed as (dst<<16)|src -----------
// Register-staged: each thread owns <= KPT edges, packs them once (no second
// global read of edge_index). 3-phase: LDS hist -> reserve chunks -> scatter.
__global__ __launch_bounds__(1024) void k_part(
        const int* __restrict__ ei, int* __restrict__ bfill,
        unsigned int* __restrict__ edges, int E, int nb) {
    __shared__ int h[MAXBUCK];
    __shared__ int chunk[MAXBUCK];
    __shared__ int cur[MAXBUCK];
    __shared__ int s_not64;
    if (threadIdx.x == 0) s_not64 = 0;
    for (int i = threadIdx.x; i < nb; i += 1024) h[i] = 0;
    __syncthreads();
    if (threadIdx.x < 256 && ei[2 * threadIdx.x + 1] != 0) s_not64 = 1;
    __syncthreads();
    int is64 = s_not64 ? 0 : 1;
    int per = (E + gridDim.x - 1) / gridDim.x;   // per <= 1024*KPT by grid calc
    int e0 = blockIdx.x * per;
    int e1 = min(e0 + per, E);

    unsigned int ed[KPT];
#pragma unroll
    for (int k = 0; k < KPT; ++k) {
        int i = e0 + threadIdx.x + k * 1024;
        if (i < e1) {
            unsigned int s = (unsigned int)load_idx(ei, i, is64);
            unsigned int d = (unsigned int)load_idx(ei, (long long)E + i, is64);
            ed[k] = (d << 16) | s;
            atomicAdd(&h[d >> 6], 1);
        }
    }
    __syncthreads();
    for (int i = threadIdx.x; i < nb; i += 1024) {
        int c = h[i];
        chunk[i] = c ? atomicAdd(&bfill[i], c) : 0;
        cur[i] = 0;
    }
    __syncthreads();
#pragma unroll
    for (int k = 0; k < KPT; ++k) {
        int i = e0 + threadIdx.x + k * 1024;
        if (i < e1) {
            int b = (int)(ed[k] >> 22);          // = dst >> 6
            int r = atomicAdd(&cur[b], 1);
            edges[chunk[b] + r] = ed[k];
        }
    }
}

// ------- per-bucket counting sort into ushort CSR + per-node count/ptr -------
// One block per bucket. LDS histogram doubles as per-node degree (count[v])
// and, scanned, as the CSR row pointer (ptr[v]).
template <bool INPLACE>
__global__ __launch_bounds__(256) void k_sort2(
        const unsigned int* __restrict__ edges, const int* __restrict__ bstart,
        int* __restrict__ count, int* __restrict__ ptr,
        unsigned short* __restrict__ sorted_src, int N, int E) {
    __shared__ int cnt64[BNODES];
    __shared__ int pos64[BNODES];
    __shared__ unsigned int raw[INPLACE ? SORT_LDS : 1];
    int tid = threadIdx.x;
    int vbase = blockIdx.x * BNODES;
    int es = bstart[blockIdx.x];
    int ee = bstart[blockIdx.x + 1];
    int m = ee - es;
    if (tid < BNODES) cnt64[tid] = 0;
    __syncthreads();

    if (INPLACE) {
        int mm = min(m, SORT_LDS);
        for (int i = tid; i < mm; i += 256) {
            unsigned int e = edges[es + i];
            raw[i] = e;
            atomicAdd(&cnt64[(e >> 16) & 63u], 1);
        }
        for (int i = SORT_LDS + tid; i < m; i += 256)
            atomicAdd(&cnt64[(edges[es + i] >> 16) & 63u], 1);
    } else {
        for (int i = tid; i < m; i += 256)
            atomicAdd(&cnt64[(edges[es + i] >> 16) & 63u], 1);
    }
    __syncthreads();

    if (tid < BNODES) {                      // wave 0: 64-wide exclusive scan
        int c = cnt64[tid];
        int inc = c;
#pragma unroll
        for (int d = 1; d < 64; d <<= 1) {
            int t2 = __shfl_up(inc, d, 64);
            if (tid >= d) inc += t2;
        }
        int off = inc - c;
        pos64[tid] = es + off;
        int v = vbase + tid;
        if (v < N) {
            count[v] = c;
            ptr[v] = es + off;
        }
    }
    __syncthreads();

    if (INPLACE) {
        int mm = min(m, SORT_LDS);
        for (int i = tid; i < mm; i += 256) {
            unsigned int e = raw[i];
            int p = atomicAdd(&pos64[(e >> 16) & 63u], 1);
            sorted_src[p] = (unsigned short)(e & 0xFFFFu);
        }
        for (int i = SORT_LDS + tid; i < m; i += 256) {   // overflow: ~never
            unsigned int e = edges[es + i];
            int p = atomicAdd(&pos64[(e >> 16) & 63u], 1);
            sorted_src[p] = (unsigned short)(e & 0xFFFFu);
        }
    } else {
        for (int i = tid; i < m; i += 256) {
            unsigned int e = edges[es + i];
            int p = atomicAdd(&pos64[(e >> 16) & 63u], 1);
            sorted_src[p] = (unsigned short)(e & 0xFFFFu);
        }
    }
}

// ------- per-node factors + y = bf16(dinv * x) (one float4 -> ushort4) ------
__global__ void k_finalize(const int* __restrict__ count, const float* __restrict__ x,
                           float* __restrict__ scale, unsigned short* __restrict__ y,
                           int N) {
    int t = blockIdx.x * blockDim.x + threadIdx.x;   // over N*16 float4s
    if (t >= N * 16) return;
    int v = t >> 4;
    float dg = (float)(count[v] + 1);                // +1 self loop
    float dv = rsqrtf(dg);
    if ((t & 15) == 0) scale[v] = dv / dg;           // dinv[v]/deg[v]
    float4 xv = ((const float4*)x)[t];
    ushort4 o;
    o.x = f2bf(xv.x * dv); o.y = f2bf(xv.y * dv);
    o.z = f2bf(xv.z * dv); o.w = f2bf(xv.w * dv);
    ((ushort4*)y)[t] = o;
}

// ---------------- gather: agg_out[v] = scale[v] * (y[v] + sum y[src]) --------
__global__ __launch_bounds__(256) void k_gather(
        const unsigned short* __restrict__ y, const float* __restrict__ scale,
        const int* __restrict__ ptr, const int* __restrict__ count,
        const unsigned short* __restrict__ sorted_src,
        float* __restrict__ agg_out, int N) {
    int wave = threadIdx.x >> 6;
    int lane = threadIdx.x & 63;
    int vbase = blockIdx.x * 16 + wave * 4;

    for (int vi = 0; vi < 4; ++vi) {
        int v = vbase + vi;
        if (v >= N) return;
        int start = ptr[v];
        int cnt = count[v];
        float sc = scale[v];
        float a0 = bf2f(y[(size_t)v * NFEAT + lane]);   // self-loop term
        float a1 = 0.f, a2 = 0.f, a3 = 0.f, a4 = 0.f, a5 = 0.f, a6 = 0.f, a7 = 0.f;

        for (int c = 0; c < cnt; c += 64) {
            int m = min(64, cnt - c);
            int s_l = 0;
            if (lane < m) s_l = (int)sorted_src[start + c + lane];
            int j = 0;
            for (; j + 8 <= m; j += 8) {
                int s0 = __shfl(s_l, j + 0, 64), s1 = __shfl(s_l, j + 1, 64);
                int s2 = __shfl(s_l, j + 2, 64), s3 = __shfl(s_l, j + 3, 64);
                int s4 = __shfl(s_l, j + 4, 64), s5 = __shfl(s_l, j + 5, 64);
                int s6 = __shfl(s_l, j + 6, 64), s7 = __shfl(s_l, j + 7, 64);
                a0 += bf2f(y[(size_t)s0 * NFEAT + lane]);
                a1 += bf2f(y[(size_t)s1 * NFEAT + lane]);
                a2 += bf2f(y[(size_t)s2 * NFEAT + lane]);
                a3 += bf2f(y[(size_t)s3 * NFEAT + lane]);
                a4 += bf2f(y[(size_t)s4 * NFEAT + lane]);
                a5 += bf2f(y[(size_t)s5 * NFEAT + lane]);
                a6 += bf2f(y[(size_t)s6 * NFEAT + lane]);
                a7 += bf2f(y[(size_t)s7 * NFEAT + lane]);
            }
            for (; j < m; ++j) {
                int s0 = __shfl(s_l, j, 64);
                a0 += bf2f(y[(size_t)s0 * NFEAT + lane]);
            }
        }
        float a = ((a0 + a1) + (a2 + a3)) + ((a4 + a5) + (a6 + a7));
        agg_out[(size_t)v * NFEAT + lane] = a * sc;
    }
}

// ------- epilogue split passes: 64 weight VGPRs each (fits the ~84 budget) ---
// R13/R14 lesson: the fused dual-GEMM needs ~150 VGPRs; the allocator grants
// ~84 regardless of launch_bounds -> weight reloads -> VMEM-bound (46us).
// Split: pass A keeps only w1r[64] resident, pass B only w2r[64].
__global__ __launch_bounds__(256, 1) void k_epiA(
        const float* __restrict__ agg, const float* __restrict__ W1,
        float* __restrict__ out, int N) {
    int gw = (blockIdx.x * 256 + threadIdx.x) >> 6;
    int lane = threadIdx.x & 63;
    float w1r[NFEAT];
#pragma unroll
    for (int k = 0; k < NFEAT; ++k) w1r[k] = W1[k * NFEAT + lane];
    int v0 = gw * NPW;
    int v1 = min(v0 + NPW, N);
    for (int v = v0; v < v1; ++v) {
        const float4* ar = (const float4*)(agg + (size_t)v * NFEAT);
        float acc1a = 0.f, acc1b = 0.f;
#pragma unroll
        for (int q = 0; q < NFEAT / 4; ++q) {
            float4 a4 = ar[q];               // wave-uniform address
            acc1a = fmaf(a4.x, w1r[4 * q + 0], acc1a);
            acc1b = fmaf(a4.y, w1r[4 * q + 1], acc1b);
            acc1a = fmaf(a4.z, w1r[4 * q + 2], acc1a);
            acc1b = fmaf(a4.w, w1r[4 * q + 3], acc1b);
        }
        out[(size_t)v * NFEAT + lane] = fmaxf(acc1a + acc1b, 0.0f);
    }
}

__global__ __launch_bounds__(256, 1) void k_epiB(
        const float* __restrict__ agg, const float* __restrict__ W2,
        float* __restrict__ out, int N) {
    int gw = (blockIdx.x * 256 + threadIdx.x) >> 6;
    int lane = threadIdx.x & 63;
    float w2r[NFEAT];
#pragma unroll
    for (int k = 0; k < NFEAT; ++k) w2r[k] = W2[k * NFEAT + lane];
    int v0 = gw * NPW;
    int v1 = min(v0 + NPW, N);
    for (int v = v0; v < v1; ++v) {
        const float4* ar = (const float4*)(agg + (size_t)v * NFEAT);
        float acc2a = 0.f, acc2b = 0.f;
#pragma unroll
        for (int q = 0; q < NFEAT / 4; ++q) {
            float4 a4 = ar[q];               // wave-uniform address
            acc2a = fmaf(a4.x, w2r[4 * q + 0], acc2a);
            acc2b = fmaf(a4.y, w2r[4 * q + 1], acc2b);
            acc2a = fmaf(a4.z, w2r[4 * q + 2], acc2a);
            acc2b = fmaf(a4.w, w2r[4 * q + 3], acc2b);
        }
        float sig = 1.0f / (1.0f + __expf(-(acc2a + acc2b)));
        size_t o = (size_t)v * NFEAT + lane;
        out[o] = out[o] * sig;               // read+write once; no alias reuse
    }
}

// ------- fallback epilogue (R10 proven): shfl GEMM in place on d_out ---------
__global__ __launch_bounds__(256) void k_epi(
        float* __restrict__ io, const float* __restrict__ W1,
        const float* __restrict__ W2, int N) {
    __shared__ float w1[NFEAT * NFEAT];
    __shared__ float w2[NFEAT * NFEAT];
    for (int i = threadIdx.x; i < NFEAT * NFEAT; i += 256) {
        w1[i] = W1[i];
        w2[i] = W2[i];
    }
    __syncthreads();
    int wave = threadIdx.x >> 6;
    int lane = threadIdx.x & 63;
    for (int v = blockIdx.x * 4 + wave; v < N; v += gridDim.x * 4) {
        float a = io[(size_t)v * NFEAT + lane];
        float acc1 = 0.0f, acc2 = 0.0f;
#pragma unroll
        for (int k = 0; k < NFEAT; ++k) {
            float ak = __shfl(a, k, 64);
            acc1 = fmaf(ak, w1[k * NFEAT + lane], acc1);
            acc2 = fmaf(ak, w2[k * NFEAT + lane], acc2);
        }
        float x1 = fmaxf(acc1, 0.0f);
        float x2 = 1.0f / (1.0f + __expf(-acc2));
        io[(size_t)v * NFEAT + lane] = x1 * x2;
    }
}

extern "C" void kernel_launch(void* const* d_in, const int* in_sizes, int n_in,
                              void* d_out, int out_size, void* d_ws, size_t ws_size,
                              hipStream_t stream) {
    const float* x  = (const float*)d_in[0];
    const int*   ei = (const int*)d_in[1];
    const float* W1 = (const float*)d_in[2];
    const float* W2 = (const float*)d_in[3];
    float* out = (float*)d_out;

    const int N = in_sizes[0] / NFEAT;       // 50000 (<= 65536: edge packing)
    const int E = in_sizes[1] / 2;           // 1,600,000
    const int nb = (N + BNODES - 1) / BNODES;   // 782 buckets

    // workspace layout (256B-aligned slices)
    char* ws = (char*)d_ws;
    size_t off = 0;
    auto alloc = [&](size_t bytes) {
        char* p = ws + off;
        off = (off + bytes + 255) & ~(size_t)255;
        return p;
    };
    int*   count  = (int*)alloc((size_t)N * 4);
    float* scale  = (float*)alloc((size_t)N * 4);
    int*   ptr    = (int*)alloc((size_t)N * 4);
    int*   bcnt   = (int*)alloc((size_t)MAXBUCK * 4);
    int*   bstart = (int*)alloc((size_t)(MAXBUCK + 1) * 4);
    int*   bfill  = (int*)alloc((size_t)MAXBUCK * 4);

    // T1 layout: agg (f32, N*64) OVERLAYS the edges region (disjoint
    // lifetimes: edges dies at k_sort2, agg born at k_gather).
    size_t aggB   = (size_t)N * NFEAT * 4;
    size_t edgeB  = (size_t)E * 4;
    size_t regB   = aggB > edgeB ? aggB : edgeB;
    size_t t1_need = off + regB + (size_t)N * NFEAT * 2 + (size_t)E * 2 + 1024;

    k_zero<<<1, 1024, 0, stream>>>(bcnt, MAXBUCK);
    k_histb<<<256, 256, 0, stream>>>(ei, bcnt, E, nb);
    k_bscan<<<1, 1024, 0, stream>>>(bcnt, bstart, bfill, nb, E);
    int gpart = (E + 1024 * KPT - 1) / (1024 * KPT);

    if (ws_size >= t1_need) {
        // ---- T1: separate agg, two single-matrix register epilogues ----
        char* reg = (char*)alloc(regB);
        unsigned int*   edges      = (unsigned int*)reg;
        float*          agg        = (float*)reg;
        unsigned short* y          = (unsigned short*)alloc((size_t)N * NFEAT * 2);
        unsigned short* sorted_src = (unsigned short*)alloc((size_t)E * 2);

        k_part<<<gpart, 1024, 0, stream>>>(ei, bfill, edges, E, nb);
        k_sort2<false><<<nb, 256, 0, stream>>>(edges, bstart, count, ptr,
                                               sorted_src, N, E);
        k_finalize<<<(N * 16 + 255) / 256, 256, 0, stream>>>(count, x, scale, y, N);
        k_gather<<<(N + 15) / 16, 256, 0, stream>>>(y, scale, ptr, count,
                                                    sorted_src, agg, N);
        int nwaves = (N + NPW - 1) / NPW;
        int nblk = (nwaves + 3) / 4;
        k_epiA<<<nblk, 256, 0, stream>>>(agg, W1, out, N);
        k_epiB<<<nblk, 256, 0, stream>>>(agg, W2, out, N);
    } else {
        // ---- T2: R10 fallback (agg in d_out, shfl epilogue in place) ----
        unsigned int*   edges = (unsigned int*)alloc(edgeB);
        unsigned short* y     = (unsigned short*)alloc((size_t)N * NFEAT * 2);
        unsigned short* sorted_src;
        bool inplace;
        if (ws_size >= off + (size_t)E * 2) {
            sorted_src = (unsigned short*)alloc((size_t)E * 2);
            inplace = false;
        } else {
            sorted_src = (unsigned short*)edges;
            inplace = true;
        }
        k_part<<<gpart, 1024, 0, stream>>>(ei, bfill, edges, E, nb);
        if (inplace) {
            k_sort2<true><<<nb, 256, 0, stream>>>(edges, bstart, count, ptr,
                                                  sorted_src, N, E);
        } else {
            k_sort2<false><<<nb, 256, 0, stream>>>(edges, bstart, count, ptr,
                                                   sorted_src, N, E);
        }
        k_finalize<<<(N * 16 + 255) / 256, 256, 0, stream>>>(count, x, scale, y, N);
        k_gather<<<(N + 15) / 16, 256, 0, stream>>>(y, scale, ptr, count,
                                                    sorted_src, out, N);
        k_epi<<<512, 256, 0, stream>>>(out, W1, W2, N);
    }
}

// Round 16
// 117.912 us; speedup vs baseline: 1.5615x; 1.5615x over previous
//
#include <hip/hip_runtime.h>

#define NFEAT 64
#define BNODES 64            // nodes per dst-bucket (bucket = dst >> 6)
#define MAXBUCK 1024         // supports N <= 65536 (edge packing needs N <= 65536)
#define SORT_LDS 6144        // whole-bucket LDS staging for in-place sort path
#define KPT 4                // edges per thread in k_part (register-staged)

__device__ __forceinline__ int load_idx(const int* __restrict__ ei, long long elem, int is64) {
    return is64 ? ei[2 * elem] : ei[(int)elem];
}

// bf16 round-to-nearest-even-ish (RN with tie bump; fine for finite data)
__device__ __forceinline__ unsigned short f2bf(float f) {
    unsigned int u = __float_as_uint(f);
    return (unsigned short)((u + 0x7FFFu + ((u >> 16) & 1u)) >> 16);
}
__device__ __forceinline__ float bf2f(unsigned short h) {
    return __uint_as_float(((unsigned int)h) << 16);
}

// ------- zero bcnt (replaces hipMemsetAsync; one tiny block) ----------------
__global__ void k_zero(int* __restrict__ p, int n) {
    for (int i = threadIdx.x; i < n; i += 1024) p[i] = 0;
}

// ------- bucket-level histogram (782 counters; LDS hist + merge) ------------
// Self-detects int64 vs int32 edge encoding: values < 65536, so under int64
// every odd int32 word is 0 (probe 256 odd words; all-zero => int64).
__global__ __launch_bounds__(256) void k_histb(
        const int* __restrict__ ei, int* __restrict__ bcnt, int E, int nb) {
    __shared__ int h[MAXBUCK];
    __shared__ int s_not64;
    if (threadIdx.x == 0) s_not64 = 0;
    for (int i = threadIdx.x; i < nb; i += 256) h[i] = 0;
    __syncthreads();
    if (ei[2 * threadIdx.x + 1] != 0) s_not64 = 1;   // benign same-value race
    __syncthreads();
    int is64 = s_not64 ? 0 : 1;
    int per = (E + gridDim.x - 1) / gridDim.x;
    int e0 = blockIdx.x * per;
    int e1 = min(e0 + per, E);
    for (int i = e0 + threadIdx.x; i < e1; i += 256) {
        int d = load_idx(ei, (long long)E + i, is64);
        atomicAdd(&h[d >> 6], 1);
    }
    __syncthreads();
    for (int i = threadIdx.x; i < nb; i += 256)
        if (h[i]) atomicAdd(&bcnt[i], h[i]);
}

// ------- exclusive scan of bucket counts (+ sentinel) ------------------------
__global__ void k_bscan(const int* __restrict__ bcnt, int* __restrict__ bstart,
                        int* __restrict__ bfill, int nb, int E) {
    __shared__ int s[1024];
    int t = threadIdx.x;
    int mine = (t < nb) ? bcnt[t] : 0;
    s[t] = mine;
    __syncthreads();
    for (int off = 1; off < 1024; off <<= 1) {
        int v = (t >= off) ? s[t - off] : 0;
        __syncthreads();
        s[t] += v;
        __syncthreads();
    }
    if (t < nb) {
        int excl = s[t] - mine;
        bstart[t] = excl;
        bfill[t] = excl;
    }
    if (t == 0) bstart[nb] = E;   // sentinel
}

// ------- partition edges into dst-buckets, packed as (dst<<16)|src -----------
// Register-staged: each thread owns <= KPT edges, packs them once (no second
// global read of edge_index). 3-phase: LDS hist -> reserve chunks -> scatter.
__global__ __launch_bounds__(1024) void k_part(
        const int* __restrict__ ei, int* __restrict__ bfill,
        unsigned int* __restrict__ edges, int E, int nb) {
    __shared__ int h[MAXBUCK];
    __shared__ int chunk[MAXBUCK];
    __shared__ int cur[MAXBUCK];
    __shared__ int s_not64;
    if (threadIdx.x == 0) s_not64 = 0;
    for (int i = threadIdx.x; i < nb; i += 1024) h[i] = 0;
    __syncthreads();
    if (threadIdx.x < 256 && ei[2 * threadIdx.x + 1] != 0) s_not64 = 1;
    __syncthreads();
    int is64 = s_not64 ? 0 : 1;
    int per = (E + gridDim.x - 1) / gridDim.x;   // per <= 1024*KPT by grid calc
    int e0 = blockIdx.x * per;
    int e1 = min(e0 + per, E);

    unsigned int ed[KPT];
#pragma unroll
    for (int k = 0; k < KPT; ++k) {
        int i = e0 + threadIdx.x + k * 1024;
        if (i < e1) {
            unsigned int s = (unsigned int)load_idx(ei, i, is64);
            unsigned int d = (unsigned int)load_idx(ei, (long long)E + i, is64);
            ed[k] = (d << 16) | s;
            atomicAdd(&h[d >> 6], 1);
        }
    }
    __syncthreads();
    for (int i = threadIdx.x; i < nb; i += 1024) {
        int c = h[i];
        chunk[i] = c ? atomicAdd(&bfill[i], c) : 0;
        cur[i] = 0;
    }
    __syncthreads();
#pragma unroll
    for (int k = 0; k < KPT; ++k) {
        int i = e0 + threadIdx.x + k * 1024;
        if (i < e1) {
            int b = (int)(ed[k] >> 22);          // = dst >> 6
            int r = atomicAdd(&cur[b], 1);
            edges[chunk[b] + r] = ed[k];
        }
    }
}

// ------- per-bucket counting sort into ushort CSR + per-node count/ptr -------
template <bool INPLACE>
__global__ __launch_bounds__(256) void k_sort2(
        const unsigned int* __restrict__ edges, const int* __restrict__ bstart,
        int* __restrict__ count, int* __restrict__ ptr,
        unsigned short* __restrict__ sorted_src, int N, int E) {
    __shared__ int cnt64[BNODES];
    __shared__ int pos64[BNODES];
    __shared__ unsigned int raw[INPLACE ? SORT_LDS : 1];
    int tid = threadIdx.x;
    int vbase = blockIdx.x * BNODES;
    int es = bstart[blockIdx.x];
    int ee = bstart[blockIdx.x + 1];
    int m = ee - es;
    if (tid < BNODES) cnt64[tid] = 0;
    __syncthreads();

    if (INPLACE) {
        int mm = min(m, SORT_LDS);
        for (int i = tid; i < mm; i += 256) {
            unsigned int e = edges[es + i];
            raw[i] = e;
            atomicAdd(&cnt64[(e >> 16) & 63u], 1);
        }
        for (int i = SORT_LDS + tid; i < m; i += 256)
            atomicAdd(&cnt64[(edges[es + i] >> 16) & 63u], 1);
    } else {
        for (int i = tid; i < m; i += 256)
            atomicAdd(&cnt64[(edges[es + i] >> 16) & 63u], 1);
    }
    __syncthreads();

    if (tid < BNODES) {                      // wave 0: 64-wide exclusive scan
        int c = cnt64[tid];
        int inc = c;
#pragma unroll
        for (int d = 1; d < 64; d <<= 1) {
            int t2 = __shfl_up(inc, d, 64);
            if (tid >= d) inc += t2;
        }
        int off = inc - c;
        pos64[tid] = es + off;
        int v = vbase + tid;
        if (v < N) {
            count[v] = c;
            ptr[v] = es + off;
        }
    }
    __syncthreads();

    if (INPLACE) {
        int mm = min(m, SORT_LDS);
        for (int i = tid; i < mm; i += 256) {
            unsigned int e = raw[i];
            int p = atomicAdd(&pos64[(e >> 16) & 63u], 1);
            sorted_src[p] = (unsigned short)(e & 0xFFFFu);
        }
        for (int i = SORT_LDS + tid; i < m; i += 256) {   // overflow: ~never
            unsigned int e = edges[es + i];
            int p = atomicAdd(&pos64[(e >> 16) & 63u], 1);
            sorted_src[p] = (unsigned short)(e & 0xFFFFu);
        }
    } else {
        for (int i = tid; i < m; i += 256) {
            unsigned int e = edges[es + i];
            int p = atomicAdd(&pos64[(e >> 16) & 63u], 1);
            sorted_src[p] = (unsigned short)(e & 0xFFFFu);
        }
    }
}

// ------- per-node factors + y = bf16(dinv * x) (one float4 -> ushort4) ------
__global__ void k_finalize(const int* __restrict__ count, const float* __restrict__ x,
                           float* __restrict__ scale, unsigned short* __restrict__ y,
                           int N) {
    int t = blockIdx.x * blockDim.x + threadIdx.x;   // over N*16 float4s
    if (t >= N * 16) return;
    int v = t >> 4;
    float dg = (float)(count[v] + 1);                // +1 self loop
    float dv = rsqrtf(dg);
    if ((t & 15) == 0) scale[v] = dv / dg;           // dinv[v]/deg[v]
    float4 xv = ((const float4*)x)[t];
    ushort4 o;
    o.x = f2bf(xv.x * dv); o.y = f2bf(xv.y * dv);
    o.z = f2bf(xv.z * dv); o.w = f2bf(xv.w * dv);
    ((ushort4*)y)[t] = o;
}

// ---------------- gather: agg_out[v] = scale[v] * (y[v] + sum y[src]) --------
__global__ __launch_bounds__(256) void k_gather(
        const unsigned short* __restrict__ y, const float* __restrict__ scale,
        const int* __restrict__ ptr, const int* __restrict__ count,
        const unsigned short* __restrict__ sorted_src,
        float* __restrict__ agg_out, int N) {
    int wave = threadIdx.x >> 6;
    int lane = threadIdx.x & 63;
    int vbase = blockIdx.x * 16 + wave * 4;

    for (int vi = 0; vi < 4; ++vi) {
        int v = vbase + vi;
        if (v >= N) return;
        int start = ptr[v];
        int cnt = count[v];
        float sc = scale[v];
        float a0 = bf2f(y[(size_t)v * NFEAT + lane]);   // self-loop term
        float a1 = 0.f, a2 = 0.f, a3 = 0.f, a4 = 0.f, a5 = 0.f, a6 = 0.f, a7 = 0.f;

        for (int c = 0; c < cnt; c += 64) {
            int m = min(64, cnt - c);
            int s_l = 0;
            if (lane < m) s_l = (int)sorted_src[start + c + lane];
            int j = 0;
            for (; j + 8 <= m; j += 8) {
                int s0 = __shfl(s_l, j + 0, 64), s1 = __shfl(s_l, j + 1, 64);
                int s2 = __shfl(s_l, j + 2, 64), s3 = __shfl(s_l, j + 3, 64);
                int s4 = __shfl(s_l, j + 4, 64), s5 = __shfl(s_l, j + 5, 64);
                int s6 = __shfl(s_l, j + 6, 64), s7 = __shfl(s_l, j + 7, 64);
                a0 += bf2f(y[(size_t)s0 * NFEAT + lane]);
                a1 += bf2f(y[(size_t)s1 * NFEAT + lane]);
                a2 += bf2f(y[(size_t)s2 * NFEAT + lane]);
                a3 += bf2f(y[(size_t)s3 * NFEAT + lane]);
                a4 += bf2f(y[(size_t)s4 * NFEAT + lane]);
                a5 += bf2f(y[(size_t)s5 * NFEAT + lane]);
                a6 += bf2f(y[(size_t)s6 * NFEAT + lane]);
                a7 += bf2f(y[(size_t)s7 * NFEAT + lane]);
            }
            for (; j < m; ++j) {
                int s0 = __shfl(s_l, j, 64);
                a0 += bf2f(y[(size_t)s0 * NFEAT + lane]);
            }
        }
        float a = ((a0 + a1) + (a2 + a3)) + ((a4 + a5) + (a6 + a7));
        agg_out[(size_t)v * NFEAT + lane] = a * sc;
    }
}

// ------- epilogue v6: LDS a-tile, lane = node, wave = 16-column slice --------
// R15 lesson: uniform a-row VMEM loads are latency-serialized (47us @ 3125
// waves); shfl/LDS broadcast is DS-bound (48us). Here NO broadcast exists:
// block stages a 64x64 a-tile coalesced into padded LDS (at[v*65+k]; read
// at[lane*65+k] -> bank (lane+k)%32 = 2-way = free). Wave w computes columns
// cb=w*16..+16 for BOTH matrices: per k, one ds_read_b32 + 32 FMAs into
// acc1[16]/acc2[16] (static unroll, ~32 regs). Weight address k*64+cb+c is
// wave-uniform (cb via readfirstlane) -> scalar K$ loads. Store: each lane
// writes cols cb..cb+16 of its own row = one full 64B line (4 float4s).
__global__ __launch_bounds__(256) void k_epi6(
        const float* __restrict__ agg, const float* __restrict__ W1,
        const float* __restrict__ W2, float* __restrict__ out, int N) {
    __shared__ float at[64 * 65];
    int tid = threadIdx.x;
    int lane = tid & 63;
    int v0 = blockIdx.x * 64;

    // stage 64x64 tile, coalesced float4 reads, padded b32 writes
    const float4* agg4 = (const float4*)agg;
    for (int i = tid; i < 64 * 16; i += 256) {
        int v = i >> 4, j = i & 15;
        float4 q;
        if (v0 + v < N) q = agg4[(size_t)(v0 + v) * 16 + j];
        else { q.x = q.y = q.z = q.w = 0.f; }
        float* r = &at[v * 65 + j * 4];
        r[0] = q.x; r[1] = q.y; r[2] = q.z; r[3] = q.w;
    }
    __syncthreads();

    int cb = __builtin_amdgcn_readfirstlane((tid >> 6) * 16);   // wave-uniform
    float acc1[16], acc2[16];
#pragma unroll
    for (int c = 0; c < 16; ++c) { acc1[c] = 0.f; acc2[c] = 0.f; }

    for (int k = 0; k < NFEAT; ++k) {
        float ak = at[lane * 65 + k];
        const float* w1k = W1 + (size_t)k * NFEAT + cb;
        const float* w2k = W2 + (size_t)k * NFEAT + cb;
#pragma unroll
        for (int c = 0; c < 16; ++c) {
            acc1[c] = fmaf(ak, w1k[c], acc1[c]);
            acc2[c] = fmaf(ak, w2k[c], acc2[c]);
        }
    }

    int v = v0 + lane;
    if (v < N) {
        float4* o4 = (float4*)(out + (size_t)v * NFEAT + cb);
#pragma unroll
        for (int g = 0; g < 4; ++g) {
            float4 q;
            float r0 = fmaxf(acc1[4 * g + 0], 0.f), s0 = 1.f / (1.f + __expf(-acc2[4 * g + 0]));
            float r1 = fmaxf(acc1[4 * g + 1], 0.f), s1 = 1.f / (1.f + __expf(-acc2[4 * g + 1]));
            float r2 = fmaxf(acc1[4 * g + 2], 0.f), s2 = 1.f / (1.f + __expf(-acc2[4 * g + 2]));
            float r3 = fmaxf(acc1[4 * g + 3], 0.f), s3 = 1.f / (1.f + __expf(-acc2[4 * g + 3]));
            q.x = r0 * s0; q.y = r1 * s1; q.z = r2 * s2; q.w = r3 * s3;
            o4[g] = q;
        }
    }
}

// ------- fallback epilogue (R10 proven): shfl GEMM in place on d_out ---------
__global__ __launch_bounds__(256) void k_epi(
        float* __restrict__ io, const float* __restrict__ W1,
        const float* __restrict__ W2, int N) {
    __shared__ float w1[NFEAT * NFEAT];
    __shared__ float w2[NFEAT * NFEAT];
    for (int i = threadIdx.x; i < NFEAT * NFEAT; i += 256) {
        w1[i] = W1[i];
        w2[i] = W2[i];
    }
    __syncthreads();
    int wave = threadIdx.x >> 6;
    int lane = threadIdx.x & 63;
    for (int v = blockIdx.x * 4 + wave; v < N; v += gridDim.x * 4) {
        float a = io[(size_t)v * NFEAT + lane];
        float acc1 = 0.0f, acc2 = 0.0f;
#pragma unroll
        for (int k = 0; k < NFEAT; ++k) {
            float ak = __shfl(a, k, 64);
            acc1 = fmaf(ak, w1[k * NFEAT + lane], acc1);
            acc2 = fmaf(ak, w2[k * NFEAT + lane], acc2);
        }
        float x1 = fmaxf(acc1, 0.0f);
        float x2 = 1.0f / (1.0f + __expf(-acc2));
        io[(size_t)v * NFEAT + lane] = x1 * x2;
    }
}

extern "C" void kernel_launch(void* const* d_in, const int* in_sizes, int n_in,
                              void* d_out, int out_size, void* d_ws, size_t ws_size,
                              hipStream_t stream) {
    const float* x  = (const float*)d_in[0];
    const int*   ei = (const int*)d_in[1];
    const float* W1 = (const float*)d_in[2];
    const float* W2 = (const float*)d_in[3];
    float* out = (float*)d_out;

    const int N = in_sizes[0] / NFEAT;       // 50000 (<= 65536: edge packing)
    const int E = in_sizes[1] / 2;           // 1,600,000
    const int nb = (N + BNODES - 1) / BNODES;   // 782 buckets

    // workspace layout (256B-aligned slices)
    char* ws = (char*)d_ws;
    size_t off = 0;
    auto alloc = [&](size_t bytes) {
        char* p = ws + off;
        off = (off + bytes + 255) & ~(size_t)255;
        return p;
    };
    int*   count  = (int*)alloc((size_t)N * 4);
    float* scale  = (float*)alloc((size_t)N * 4);
    int*   ptr    = (int*)alloc((size_t)N * 4);
    int*   bcnt   = (int*)alloc((size_t)MAXBUCK * 4);
    int*   bstart = (int*)alloc((size_t)(MAXBUCK + 1) * 4);
    int*   bfill  = (int*)alloc((size_t)MAXBUCK * 4);

    // T1 layout: agg (f32, N*64) OVERLAYS the edges region (disjoint
    // lifetimes: edges dies at k_sort2, agg born at k_gather).
    size_t aggB   = (size_t)N * NFEAT * 4;
    size_t edgeB  = (size_t)E * 4;
    size_t regB   = aggB > edgeB ? aggB : edgeB;
    size_t t1_need = off + regB + (size_t)N * NFEAT * 2 + (size_t)E * 2 + 1024;

    k_zero<<<1, 1024, 0, stream>>>(bcnt, MAXBUCK);
    k_histb<<<256, 256, 0, stream>>>(ei, bcnt, E, nb);
    k_bscan<<<1, 1024, 0, stream>>>(bcnt, bstart, bfill, nb, E);
    int gpart = (E + 1024 * KPT - 1) / (1024 * KPT);

    if (ws_size >= t1_need) {
        // ---- T1: separate agg, LDS-tiled register epilogue ----
        char* reg = (char*)alloc(regB);
        unsigned int*   edges      = (unsigned int*)reg;
        float*          agg        = (float*)reg;
        unsigned short* y          = (unsigned short*)alloc((size_t)N * NFEAT * 2);
        unsigned short* sorted_src = (unsigned short*)alloc((size_t)E * 2);

        k_part<<<gpart, 1024, 0, stream>>>(ei, bfill, edges, E, nb);
        k_sort2<false><<<nb, 256, 0, stream>>>(edges, bstart, count, ptr,
                                               sorted_src, N, E);
        k_finalize<<<(N * 16 + 255) / 256, 256, 0, stream>>>(count, x, scale, y, N);
        k_gather<<<(N + 15) / 16, 256, 0, stream>>>(y, scale, ptr, count,
                                                    sorted_src, agg, N);
        k_epi6<<<(N + 63) / 64, 256, 0, stream>>>(agg, W1, W2, out, N);
    } else {
        // ---- T2: R10 fallback (agg in d_out, shfl epilogue in place) ----
        unsigned int*   edges = (unsigned int*)alloc(edgeB);
        unsigned short* y     = (unsigned short*)alloc((size_t)N * NFEAT * 2);
        unsigned short* sorted_src;
        bool inplace;
        if (ws_size >= off + (size_t)E * 2) {
            sorted_src = (unsigned short*)alloc((size_t)E * 2);
            inplace = false;
        } else {
            sorted_src = (unsigned short*)edges;
            inplace = true;
        }
        k_part<<<gpart, 1024, 0, stream>>>(ei, bfill, edges, E, nb);
        if (inplace) {
            k_sort2<true><<<nb, 256, 0, stream>>>(edges, bstart, count, ptr,
                                                  sorted_src, N, E);
        } else {
            k_sort2<false><<<nb, 256, 0, stream>>>(edges, bstart, count, ptr,
                                                   sorted_src, N, E);
        }
        k_finalize<<<(N * 16 + 255) / 256, 256, 0, stream>>>(count, x, scale, y, N);
        k_gather<<<(N + 15) / 16, 256, 0, stream>>>(y, scale, ptr, count,
                                                    sorted_src, out, N);
        k_epi<<<512, 256, 0, stream>>>(out, W1, W2, N);
    }
}

// Round 17
// 114.674 us; speedup vs baseline: 1.6055x; 1.0282x over previous
//
#include <hip/hip_runtime.h>

#define NFEAT 64
#define BNODES 64            // nodes per dst-bucket (bucket = dst >> 6)
#define MAXBUCK 1024         // supports N <= 65536 (edge packing needs N <= 65536)
#define SORT_LDS 6144        // whole-bucket LDS staging for in-place sort path
#define KPT 4                // edges per thread in k_part (register-staged)

__device__ __forceinline__ unsigned short f2bf(float f) {
    unsigned int u = __float_as_uint(f);
    return (unsigned short)((u + 0x7FFFu + ((u >> 16) & 1u)) >> 16);
}
__device__ __forceinline__ float bf2f(unsigned short h) {
    return __uint_as_float(((unsigned int)h) << 16);
}

// ------- zero bcnt (one tiny block) -----------------------------------------
__global__ void k_zero(int* __restrict__ p, int n) {
    for (int i = threadIdx.x; i < n; i += 1024) p[i] = 0;
}

// ------- bucket-level histogram (782 counters; LDS hist + merge) ------------
// Self-detects int64 vs int32 edge encoding: values < 65536, so under int64
// every odd int32 word is 0 (probe 256 odd words; all-zero => int64).
// int64 path uses int2 loads (full-line utilization vs stride-2 scalar).
__global__ __launch_bounds__(256) void k_histb(
        const int* __restrict__ ei, int* __restrict__ bcnt, int E, int nb) {
    __shared__ int h[MAXBUCK];
    __shared__ int s_not64;
    if (threadIdx.x == 0) s_not64 = 0;
    for (int i = threadIdx.x; i < nb; i += 256) h[i] = 0;
    __syncthreads();
    if (ei[2 * threadIdx.x + 1] != 0) s_not64 = 1;   // benign same-value race
    __syncthreads();
    int is64 = s_not64 ? 0 : 1;
    int per = (E + gridDim.x - 1) / gridDim.x;
    int e0 = blockIdx.x * per;
    int e1 = min(e0 + per, E);
    if (is64) {
        const int2* d64 = (const int2*)ei + E;       // dst half as int2
        for (int i = e0 + threadIdx.x; i < e1; i += 256)
            atomicAdd(&h[d64[i].x >> 6], 1);
    } else {
        for (int i = e0 + threadIdx.x; i < e1; i += 256)
            atomicAdd(&h[ei[E + i] >> 6], 1);
    }
    __syncthreads();
    for (int i = threadIdx.x; i < nb; i += 256)
        if (h[i]) atomicAdd(&bcnt[i], h[i]);
}

// ------- exclusive scan of bucket counts (+ sentinel) ------------------------
__global__ void k_bscan(const int* __restrict__ bcnt, int* __restrict__ bstart,
                        int* __restrict__ bfill, int nb, int E) {
    __shared__ int s[1024];
    int t = threadIdx.x;
    int mine = (t < nb) ? bcnt[t] : 0;
    s[t] = mine;
    __syncthreads();
    for (int off = 1; off < 1024; off <<= 1) {
        int v = (t >= off) ? s[t - off] : 0;
        __syncthreads();
        s[t] += v;
        __syncthreads();
    }
    if (t < nb) {
        int excl = s[t] - mine;
        bstart[t] = excl;
        bfill[t] = excl;
    }
    if (t == 0) bstart[nb] = E;   // sentinel
}

// ------- partition edges into dst-buckets, packed as (dst<<16)|src -----------
// Register-staged: each thread owns <= KPT edges, packs them once. 3-phase:
// LDS hist -> reserve chunks -> scatter. int64 path uses int2 loads.
__global__ __launch_bounds__(1024) void k_part(
        const int* __restrict__ ei, int* __restrict__ bfill,
        unsigned int* __restrict__ edges, int E, int nb) {
    __shared__ int h[MAXBUCK];
    __shared__ int chunk[MAXBUCK];
    __shared__ int cur[MAXBUCK];
    __shared__ int s_not64;
    if (threadIdx.x == 0) s_not64 = 0;
    for (int i = threadIdx.x; i < nb; i += 1024) h[i] = 0;
    __syncthreads();
    if (threadIdx.x < 256 && ei[2 * threadIdx.x + 1] != 0) s_not64 = 1;
    __syncthreads();
    int is64 = s_not64 ? 0 : 1;
    int per = (E + gridDim.x - 1) / gridDim.x;   // per <= 1024*KPT by grid calc
    int e0 = blockIdx.x * per;
    int e1 = min(e0 + per, E);

    unsigned int ed[KPT];
    if (is64) {
        const int2* s64 = (const int2*)ei;
        const int2* d64 = s64 + E;
#pragma unroll
        for (int k = 0; k < KPT; ++k) {
            int i = e0 + threadIdx.x + k * 1024;
            if (i < e1) {
                unsigned int s = (unsigned int)s64[i].x;
                unsigned int d = (unsigned int)d64[i].x;
                ed[k] = (d << 16) | s;
                atomicAdd(&h[d >> 6], 1);
            }
        }
    } else {
#pragma unroll
        for (int k = 0; k < KPT; ++k) {
            int i = e0 + threadIdx.x + k * 1024;
            if (i < e1) {
                unsigned int s = (unsigned int)ei[i];
                unsigned int d = (unsigned int)ei[E + i];
                ed[k] = (d << 16) | s;
                atomicAdd(&h[d >> 6], 1);
            }
        }
    }
    __syncthreads();
    for (int i = threadIdx.x; i < nb; i += 1024) {
        int c = h[i];
        chunk[i] = c ? atomicAdd(&bfill[i], c) : 0;
        cur[i] = 0;
    }
    __syncthreads();
#pragma unroll
    for (int k = 0; k < KPT; ++k) {
        int i = e0 + threadIdx.x + k * 1024;
        if (i < e1) {
            int b = (int)(ed[k] >> 22);          // = dst >> 6
            int r = atomicAdd(&cur[b], 1);
            edges[chunk[b] + r] = ed[k];
        }
    }
}

// ------- fused: per-bucket counting sort into ushort CSR + count/ptr
//         + per-node factors + y = bf16(dinv * x)  (absorbs old k_finalize) --
template <bool INPLACE>
__global__ __launch_bounds__(256) void k_sort3(
        const unsigned int* __restrict__ edges, const int* __restrict__ bstart,
        const float* __restrict__ x, int* __restrict__ count,
        int* __restrict__ ptr, float* __restrict__ scale,
        unsigned short* __restrict__ y, unsigned short* __restrict__ sorted_src,
        int N, int E) {
    __shared__ int cnt64[BNODES];
    __shared__ int pos64[BNODES];
    __shared__ unsigned int raw[INPLACE ? SORT_LDS : 1];
    int tid = threadIdx.x;
    int vbase = blockIdx.x * BNODES;
    int es = bstart[blockIdx.x];
    int ee = bstart[blockIdx.x + 1];
    int m = ee - es;
    if (tid < BNODES) cnt64[tid] = 0;
    __syncthreads();

    if (INPLACE) {
        int mm = min(m, SORT_LDS);
        for (int i = tid; i < mm; i += 256) {
            unsigned int e = edges[es + i];
            raw[i] = e;
            atomicAdd(&cnt64[(e >> 16) & 63u], 1);
        }
        for (int i = SORT_LDS + tid; i < m; i += 256)
            atomicAdd(&cnt64[(edges[es + i] >> 16) & 63u], 1);
    } else {
        for (int i = tid; i < m; i += 256)
            atomicAdd(&cnt64[(edges[es + i] >> 16) & 63u], 1);
    }
    __syncthreads();

    if (tid < BNODES) {                      // wave 0: 64-wide exclusive scan
        int c = cnt64[tid];
        int inc = c;
#pragma unroll
        for (int d = 1; d < 64; d <<= 1) {
            int t2 = __shfl_up(inc, d, 64);
            if (tid >= d) inc += t2;
        }
        int off = inc - c;
        pos64[tid] = es + off;
        int v = vbase + tid;
        if (v < N) {
            count[v] = c;
            ptr[v] = es + off;
            float dg = (float)(c + 1);
            scale[v] = rsqrtf(dg) / dg;
        }
    }
    __syncthreads();

    // scatter srcs into CSR
    if (INPLACE) {
        int mm = min(m, SORT_LDS);
        for (int i = tid; i < mm; i += 256) {
            unsigned int e = raw[i];
            int p = atomicAdd(&pos64[(e >> 16) & 63u], 1);
            sorted_src[p] = (unsigned short)(e & 0xFFFFu);
        }
        for (int i = SORT_LDS + tid; i < m; i += 256) {   // overflow: ~never
            unsigned int e = edges[es + i];
            int p = atomicAdd(&pos64[(e >> 16) & 63u], 1);
            sorted_src[p] = (unsigned short)(e & 0xFFFFu);
        }
    } else {
        for (int i = tid; i < m; i += 256) {
            unsigned int e = edges[es + i];
            int p = atomicAdd(&pos64[(e >> 16) & 63u], 1);
            sorted_src[p] = (unsigned short)(e & 0xFFFFu);
        }
    }

    // fused finalize: y rows for this bucket's 64 nodes (coalesced float4)
    const float4* x4 = (const float4*)x;
    for (int i = tid; i < BNODES * 16; i += 256) {
        int r = i >> 4, j = i & 15;
        int v = vbase + r;
        if (v < N) {
            float dg = (float)(cnt64[r] + 1);
            float dv = rsqrtf(dg);
            float4 q = x4[(size_t)v * 16 + j];
            ushort4 o;
            o.x = f2bf(q.x * dv); o.y = f2bf(q.y * dv);
            o.z = f2bf(q.z * dv); o.w = f2bf(q.w * dv);
            ((ushort4*)y)[(size_t)v * 16 + j] = o;
        }
    }
}

// ---------------- gather: agg_out[v] = scale[v] * (y[v] + sum y[src]) --------
__global__ __launch_bounds__(256) void k_gather(
        const unsigned short* __restrict__ y, const float* __restrict__ scale,
        const int* __restrict__ ptr, const int* __restrict__ count,
        const unsigned short* __restrict__ sorted_src,
        float* __restrict__ agg_out, int N) {
    int wave = threadIdx.x >> 6;
    int lane = threadIdx.x & 63;
    int vbase = blockIdx.x * 16 + wave * 4;

    for (int vi = 0; vi < 4; ++vi) {
        int v = vbase + vi;
        if (v >= N) return;
        int start = ptr[v];
        int cnt = count[v];
        float sc = scale[v];
        float a0 = bf2f(y[(size_t)v * NFEAT + lane]);   // self-loop term
        float a1 = 0.f, a2 = 0.f, a3 = 0.f, a4 = 0.f, a5 = 0.f, a6 = 0.f, a7 = 0.f;

        for (int c = 0; c < cnt; c += 64) {
            int m = min(64, cnt - c);
            int s_l = 0;
            if (lane < m) s_l = (int)sorted_src[start + c + lane];
            int j = 0;
            for (; j + 8 <= m; j += 8) {
                int s0 = __shfl(s_l, j + 0, 64), s1 = __shfl(s_l, j + 1, 64);
                int s2 = __shfl(s_l, j + 2, 64), s3 = __shfl(s_l, j + 3, 64);
                int s4 = __shfl(s_l, j + 4, 64), s5 = __shfl(s_l, j + 5, 64);
                int s6 = __shfl(s_l, j + 6, 64), s7 = __shfl(s_l, j + 7, 64);
                a0 += bf2f(y[(size_t)s0 * NFEAT + lane]);
                a1 += bf2f(y[(size_t)s1 * NFEAT + lane]);
                a2 += bf2f(y[(size_t)s2 * NFEAT + lane]);
                a3 += bf2f(y[(size_t)s3 * NFEAT + lane]);
                a4 += bf2f(y[(size_t)s4 * NFEAT + lane]);
                a5 += bf2f(y[(size_t)s5 * NFEAT + lane]);
                a6 += bf2f(y[(size_t)s6 * NFEAT + lane]);
                a7 += bf2f(y[(size_t)s7 * NFEAT + lane]);
            }
            for (; j < m; ++j) {
                int s0 = __shfl(s_l, j, 64);
                a0 += bf2f(y[(size_t)s0 * NFEAT + lane]);
            }
        }
        float a = ((a0 + a1) + (a2 + a3)) + ((a4 + a5) + (a6 + a7));
        agg_out[(size_t)v * NFEAT + lane] = a * sc;
    }
}

// ------- epilogue v6 (R16 proven): LDS a-tile, lane = node, wave = 16 cols ---
__global__ __launch_bounds__(256) void k_epi6(
        const float* __restrict__ agg, const float* __restrict__ W1,
        const float* __restrict__ W2, float* __restrict__ out, int N) {
    __shared__ float at[64 * 65];
    int tid = threadIdx.x;
    int lane = tid & 63;
    int v0 = blockIdx.x * 64;

    const float4* agg4 = (const float4*)agg;
    for (int i = tid; i < 64 * 16; i += 256) {
        int v = i >> 4, j = i & 15;
        float4 q;
        if (v0 + v < N) q = agg4[(size_t)(v0 + v) * 16 + j];
        else { q.x = q.y = q.z = q.w = 0.f; }
        float* r = &at[v * 65 + j * 4];
        r[0] = q.x; r[1] = q.y; r[2] = q.z; r[3] = q.w;
    }
    __syncthreads();

    int cb = __builtin_amdgcn_readfirstlane((tid >> 6) * 16);   // wave-uniform
    float acc1[16], acc2[16];
#pragma unroll
    for (int c = 0; c < 16; ++c) { acc1[c] = 0.f; acc2[c] = 0.f; }

    for (int k = 0; k < NFEAT; ++k) {
        float ak = at[lane * 65 + k];
        const float* w1k = W1 + (size_t)k * NFEAT + cb;
        const float* w2k = W2 + (size_t)k * NFEAT + cb;
#pragma unroll
        for (int c = 0; c < 16; ++c) {
            acc1[c] = fmaf(ak, w1k[c], acc1[c]);
            acc2[c] = fmaf(ak, w2k[c], acc2[c]);
        }
    }

    int v = v0 + lane;
    if (v < N) {
        float4* o4 = (float4*)(out + (size_t)v * NFEAT + cb);
#pragma unroll
        for (int g = 0; g < 4; ++g) {
            float4 q;
            float r0 = fmaxf(acc1[4 * g + 0], 0.f), s0 = 1.f / (1.f + __expf(-acc2[4 * g + 0]));
            float r1 = fmaxf(acc1[4 * g + 1], 0.f), s1 = 1.f / (1.f + __expf(-acc2[4 * g + 1]));
            float r2 = fmaxf(acc1[4 * g + 2], 0.f), s2 = 1.f / (1.f + __expf(-acc2[4 * g + 2]));
            float r3 = fmaxf(acc1[4 * g + 3], 0.f), s3 = 1.f / (1.f + __expf(-acc2[4 * g + 3]));
            q.x = r0 * s0; q.y = r1 * s1; q.z = r2 * s2; q.w = r3 * s3;
            o4[g] = q;
        }
    }
}

extern "C" void kernel_launch(void* const* d_in, const int* in_sizes, int n_in,
                              void* d_out, int out_size, void* d_ws, size_t ws_size,
                              hipStream_t stream) {
    const float* x  = (const float*)d_in[0];
    const int*   ei = (const int*)d_in[1];
    const float* W1 = (const float*)d_in[2];
    const float* W2 = (const float*)d_in[3];
    float* out = (float*)d_out;

    const int N = in_sizes[0] / NFEAT;       // 50000 (<= 65536: edge packing)
    const int E = in_sizes[1] / 2;           // 1,600,000
    const int nb = (N + BNODES - 1) / BNODES;   // 782 buckets

    // workspace layout (256B-aligned slices)
    char* ws = (char*)d_ws;
    size_t off = 0;
    auto alloc = [&](size_t bytes) {
        char* p = ws + off;
        off = (off + bytes + 255) & ~(size_t)255;
        return p;
    };
    int*   count  = (int*)alloc((size_t)N * 4);
    float* scale  = (float*)alloc((size_t)N * 4);
    int*   ptr    = (int*)alloc((size_t)N * 4);
    int*   bcnt   = (int*)alloc((size_t)MAXBUCK * 4);
    int*   bstart = (int*)alloc((size_t)(MAXBUCK + 1) * 4);
    int*   bfill  = (int*)alloc((size_t)MAXBUCK * 4);

    // T1 layout: agg (f32, N*64) OVERLAYS the edges region (disjoint
    // lifetimes: edges dies at k_sort3, agg born at k_gather).
    size_t aggB   = (size_t)N * NFEAT * 4;
    size_t edgeB  = (size_t)E * 4;
    size_t regB   = aggB > edgeB ? aggB : edgeB;
    size_t t1_need = off + regB + (size_t)N * NFEAT * 2 + (size_t)E * 2 + 1024;

    k_zero<<<1, 1024, 0, stream>>>(bcnt, MAXBUCK);
    k_histb<<<256, 256, 0, stream>>>(ei, bcnt, E, nb);
    k_bscan<<<1, 1024, 0, stream>>>(bcnt, bstart, bfill, nb, E);
    int gpart = (E + 1024 * KPT - 1) / (1024 * KPT);

    if (ws_size >= t1_need) {
        // ---- T1: separate agg + CSR; fused sort+finalize; LDS-tiled epi ----
        char* reg = (char*)alloc(regB);
        unsigned int*   edges      = (unsigned int*)reg;
        float*          agg        = (float*)reg;
        unsigned short* y          = (unsigned short*)alloc((size_t)N * NFEAT * 2);
        unsigned short* sorted_src = (unsigned short*)alloc((size_t)E * 2);

        k_part<<<gpart, 1024, 0, stream>>>(ei, bfill, edges, E, nb);
        k_sort3<false><<<nb, 256, 0, stream>>>(edges, bstart, x, count, ptr,
                                               scale, y, sorted_src, N, E);
        k_gather<<<(N + 15) / 16, 256, 0, stream>>>(y, scale, ptr, count,
                                                    sorted_src, agg, N);
        k_epi6<<<(N + 63) / 64, 256, 0, stream>>>(agg, W1, W2, out, N);
    } else {
        // ---- T2: fallback — agg in d_out scratch, in-place sort, same epi --
        unsigned int*   edges = (unsigned int*)alloc(edgeB);
        unsigned short* y     = (unsigned short*)alloc((size_t)N * NFEAT * 2);
        unsigned short* sorted_src;
        bool inplace;
        if (ws_size >= off + (size_t)E * 2) {
            sorted_src = (unsigned short*)alloc((size_t)E * 2);
            inplace = false;
        } else {
            sorted_src = (unsigned short*)edges;
            inplace = true;
        }
        k_part<<<gpart, 1024, 0, stream>>>(ei, bfill, edges, E, nb);
        if (inplace) {
            k_sort3<true><<<nb, 256, 0, stream>>>(edges, bstart, x, count, ptr,
                                                  scale, y, sorted_src, N, E);
        } else {
            k_sort3<false><<<nb, 256, 0, stream>>>(edges, bstart, x, count, ptr,
                                                   scale, y, sorted_src, N, E);
        }
        k_gather<<<(N + 15) / 16, 256, 0, stream>>>(y, scale, ptr, count,
                                                    sorted_src, out, N);
        k_epi6<<<(N + 63) / 64, 256, 0, stream>>>(out, W1, W2, out, N);
    }
}